// Round 17
// baseline (3086.622 us; speedup 1.0000x reference)
//
#include <hip/hip_runtime.h>
#include <hip/hip_fp16.h>

#define BN_EPS 1e-5f
#define BUCKET 16000          // 64,000 B static LDS -> 2 WG/CU (r14-proven)

// 12 dims packed in 16 B: 4 x u32, each = (d0:11b | d1:11b | d2:10b), signed
// fixed point, range +-5.5 (inputs are N(0,1); P(|x|>5.5) ~ 2e-8).
#define QS11 186.0f            // 1023/5.5
#define QS10 92.909090f        // 511/5.5
#define QI11 0.0053763445f     // 5.5/1023
#define QI10 0.0107632094f     // 5.5/511
#define QP11 (QI11*QI11)
#define QP10 (QI10*QI10)

typedef int            v4i __attribute__((ext_vector_type(4)));
typedef unsigned       v4u __attribute__((ext_vector_type(4)));
typedef float          v4f __attribute__((ext_vector_type(4)));
typedef unsigned short u16;
typedef unsigned long long u64;

// edge record: pk = (gsrc:17 << 15) | (fp16(like) >> 1)   [like15: 15 bits]
__device__ __forceinline__ float pk_like(unsigned pk) {
    return __half2float(__ushort_as_half((u16)((pk & 0x7FFFu) << 1)));
}

__device__ __forceinline__ float2 bn_params(const double* acc,
                                            const float* bnw,
                                            const float* bnb, int E) {
    double mean = acc[0] / (double)E;
    double var  = acc[1] / (double)E - mean * mean;
    float scale = bnw[0] * rsqrtf((float)var + BN_EPS);
    float shift = bnb[0] - (float)mean * scale;
    return make_float2(scale, shift);
}

__device__ __forceinline__ int qclamp(float x, float s, int lim) {
    int q = (int)rintf(x * s);
    return min(max(q, -lim), lim);
}
__device__ __forceinline__ unsigned enc3(float a, float b, float c) {
    unsigned qa = (unsigned)qclamp(a, QS11, 1023) & 0x7FFu;
    unsigned qb = (unsigned)qclamp(b, QS11, 1023) & 0x7FFu;
    unsigned qc = (unsigned)qclamp(c, QS10, 511)  & 0x3FFu;
    return qa | (qb << 11) | (qc << 22);
}

// ---------------------------------------------------------------------------
// K0: quant-pack BOTH f32 [N][12] tables into 16 B rows (one launch).
// ---------------------------------------------------------------------------
__global__ void k_pack_quant(const float* __restrict__ src_emb,
                             const float* __restrict__ dst_emb,
                             int4* __restrict__ qs,
                             int4* __restrict__ qd, int N) {
    int t = blockIdx.x * blockDim.x + threadIdx.x;
    if (t >= 2 * N) return;
    int n = (t < N) ? t : t - N;
    const float* r = ((t < N) ? src_emb : dst_emb) + (size_t)n * 12;
    int4* dst = ((t < N) ? qs : qd) + n;
    float v[12];
    #pragma unroll
    for (int j = 0; j < 12; ++j) v[j] = r[j];
    int4 w;
    w.x = (int)enc3(v[0], v[1], v[2]);
    w.y = (int)enc3(v[3], v[4], v[5]);
    w.z = (int)enc3(v[6], v[7], v[8]);
    w.w = (int)enc3(v[9], v[10], v[11]);
    *dst = w;
}

// integer decode-dot of two 16 B rows
__device__ __forceinline__ float qdot(int4 A, int4 B) {
    int aw[4] = {A.x, A.y, A.z, A.w};
    int bw[4] = {B.x, B.y, B.z, B.w};
    int s11 = 0, s10 = 0;
    #pragma unroll
    for (int k = 0; k < 4; ++k) {
        int a0 = (aw[k] << 21) >> 21;
        int a1 = (aw[k] << 10) >> 21;
        int a2 =  aw[k] >> 22;
        int b0 = (bw[k] << 21) >> 21;
        int b1 = (bw[k] << 10) >> 21;
        int b2 =  bw[k] >> 22;
        s11 += a0 * b0 + a1 * b1;
        s10 += a2 * b2;
    }
    return (float)s11 * QP11 + (float)s10 * QP10;
}

// ---------------------------------------------------------------------------
// K1: fused dot, 8 edges/thread (r14-proven, at its L2-gather floor).
// Adds per-bucket edge counting (7 register counters, wave+block reduce,
// 7 global atomics) for the exact-region split.
// ---------------------------------------------------------------------------
__global__ __launch_bounds__(256) void k_dot(
        const int4* __restrict__ qs,
        const int4* __restrict__ qd,
        const int* __restrict__ gsrc,
        const int* __restrict__ gdst,
        unsigned* __restrict__ plane,
        double* __restrict__ acc,    // acc[0]=sum, acc[1]=sumsq
        int* __restrict__ cnt7,
        int E) {
    int e0 = (blockIdx.x * blockDim.x + threadIdx.x) * 8;
    float lsum = 0.f, lsq = 0.f;
    int c0 = 0, c1 = 0, c2 = 0, c3 = 0, c4 = 0, c5 = 0, c6 = 0;
    if (e0 + 8 <= E) {
        v4i s0 = __builtin_nontemporal_load((const v4i*)(gsrc + e0));
        v4i s1 = __builtin_nontemporal_load((const v4i*)(gsrc + e0 + 4));
        v4i d0 = __builtin_nontemporal_load((const v4i*)(gdst + e0));
        v4i d1 = __builtin_nontemporal_load((const v4i*)(gdst + e0 + 4));
        int is[8] = {s0.x, s0.y, s0.z, s0.w, s1.x, s1.y, s1.z, s1.w};
        int id[8] = {d0.x, d0.y, d0.z, d0.w, d1.x, d1.y, d1.z, d1.w};
        int4 ra[8], rb[8];
        #pragma unroll
        for (int k = 0; k < 8; ++k) {     // issue all 16 gathers up front
            ra[k] = qs[is[k]];
            rb[k] = qd[id[k]];
        }
        unsigned pk[8];
        #pragma unroll
        for (int k = 0; k < 8; ++k) {
            float d = qdot(ra[k], rb[k]);
            lsum += d;
            lsq  = fmaf(d, d, lsq);
            unsigned h = (unsigned)__half_as_ushort(__float2half(d));
            pk[k] = ((unsigned)is[k] << 15) | (h >> 1);
            int b = is[k] / BUCKET;
            c0 += (b == 0); c1 += (b == 1); c2 += (b == 2); c3 += (b == 3);
            c4 += (b == 4); c5 += (b == 5); c6 += (b == 6);
        }
        v4u o0 = {pk[0], pk[1], pk[2], pk[3]};
        v4u o1 = {pk[4], pk[5], pk[6], pk[7]};
        __builtin_nontemporal_store(o0, (v4u*)(plane + e0));
        __builtin_nontemporal_store(o1, (v4u*)(plane + e0 + 4));
    } else {
        for (int e = e0; e < E; ++e) {
            int gs = gsrc[e];
            float d = qdot(qs[gs], qd[gdst[e]]);
            lsum += d;
            lsq  += d * d;
            unsigned h = (unsigned)__half_as_ushort(__float2half(d));
            plane[e] = ((unsigned)gs << 15) | (h >> 1);
            int b = gs / BUCKET;
            c0 += (b == 0); c1 += (b == 1); c2 += (b == 2); c3 += (b == 3);
            c4 += (b == 4); c5 += (b == 5); c6 += (b == 6);
        }
    }
    for (int off = 32; off > 0; off >>= 1) {
        lsum += __shfl_down(lsum, off);
        lsq  += __shfl_down(lsq, off);
        c0 += __shfl_down(c0, off); c1 += __shfl_down(c1, off);
        c2 += __shfl_down(c2, off); c3 += __shfl_down(c3, off);
        c4 += __shfl_down(c4, off); c5 += __shfl_down(c5, off);
        c6 += __shfl_down(c6, off);
    }
    __shared__ float ssum[4], ssq[4];
    __shared__ int scnt[4][7];
    int wave = threadIdx.x >> 6, lane = threadIdx.x & 63;
    if (lane == 0) {
        ssum[wave] = lsum; ssq[wave] = lsq;
        scnt[wave][0] = c0; scnt[wave][1] = c1; scnt[wave][2] = c2;
        scnt[wave][3] = c3; scnt[wave][4] = c4; scnt[wave][5] = c5;
        scnt[wave][6] = c6;
    }
    __syncthreads();
    if (threadIdx.x == 0) {
        float ts = 0.f, tq = 0.f;
        for (int i = 0; i < 4; ++i) { ts += ssum[i]; tq += ssq[i]; }
        atomicAdd(&acc[0], (double)ts);
        atomicAdd(&acc[1], (double)tq);
    }
    if (threadIdx.x < 7) {
        int t = scnt[0][threadIdx.x] + scnt[1][threadIdx.x] +
                scnt[2][threadIdx.x] + scnt[3][threadIdx.x];
        if (t) atomicAdd(&cnt7[threadIdx.x], t);
    }
}

// ---------------------------------------------------------------------------
// K2: counting-split. Grid-stride the ordered plane once; ballot-aggregated
// append of each pk into its bucket's exact region (bases = 4-aligned prefix
// of cnt7; ONE leader atomic per wave per nonempty bin). Writes are dense
// coalesced runs; normal stores (L2 write-combining). r10-validated pattern.
// ---------------------------------------------------------------------------
__global__ __launch_bounds__(256) void k_split(
        const unsigned* __restrict__ plane,
        const int* __restrict__ cnt7,
        unsigned* __restrict__ cur,
        unsigned* __restrict__ region,
        int E, int P) {
    __shared__ unsigned sbase[8];
    if (threadIdx.x == 0) {
        unsigned run = 0;
        for (int q = 0; q < P; ++q) {
            sbase[q] = run;
            run += (unsigned)((cnt7[q] + 3) & ~3);
        }
    }
    __syncthreads();
    const int lane = threadIdx.x & 63;
    const u64 lt = (1ULL << lane) - 1ULL;
    const int stride = gridDim.x * blockDim.x;
    const int tid0 = blockIdx.x * blockDim.x + threadIdx.x;
    const int nIter = (E + stride - 1) / stride;
    for (int it = 0; it < nIter; ++it) {
        int i = tid0 + it * stride;
        int b = -1;
        unsigned pk = 0;
        if (i < E) {
            pk = __builtin_nontemporal_load(plane + i);
            b = (int)((pk >> 15) / (unsigned)BUCKET);
        }
        for (int bin = 0; bin < P; ++bin) {
            u64 m = __ballot(b == bin);
            if (m) {
                int leader = __ffsll((long long)m) - 1;
                unsigned base = 0;
                if (lane == leader)
                    base = atomicAdd(&cur[bin], (unsigned)__popcll(m));
                base = __shfl(base, leader);
                if (b == bin)
                    region[sbase[bin] + base + (unsigned)__popcll(m & lt)] = pk;
            }
        }
    }
}

// ---------------------------------------------------------------------------
// K3: SINGLE-VISIT scatter. Block (g,p) reads slice g of bucket p's exact
// region (no membership tests, 12.8 MB total across all blocks), LDS
// atomicAdd exp(), paired-u32 fp16 slab flush (r14/r15-proven).
// ---------------------------------------------------------------------------
__global__ __launch_bounds__(512) void k_bucket_scatter(
        const unsigned* __restrict__ region,
        const int* __restrict__ cnt7,
        const double* __restrict__ acc,
        const float* __restrict__ bnw,
        const float* __restrict__ bnb,
        u16* __restrict__ slab,   // [(p*G + g) * BUCKET], fp16 bits
        int E, int G, int P) {
    __shared__ float sm[BUCKET];
    __shared__ float2 s_par;
    __shared__ unsigned s_b0;
    __shared__ int s_n;
    const int g = blockIdx.x;
    const int p = blockIdx.y;
    const int lo = p * BUCKET;

    if (threadIdx.x == 0) {
        s_par = bn_params(acc, bnw, bnb, E);
        unsigned run = 0; int n = 0; unsigned b0 = 0;
        for (int q = 0; q < P; ++q) {
            int c = cnt7[q];
            if (q == p) { b0 = run; n = c; }
            run += (unsigned)((c + 3) & ~3);
        }
        s_b0 = b0; s_n = n;
    }
    for (int i = threadIdx.x; i < BUCKET; i += blockDim.x) sm[i] = 0.f;
    __syncthreads();
    const float scale = s_par.x;
    const float shift = s_par.y;
    const unsigned b0 = s_b0;
    const int n = s_n;

    int span = ((n + G - 1) / G + 3) & ~3;
    const int i0 = g * span;
    const int i1 = min(i0 + span, n);

    for (int i = i0 + (int)threadIdx.x * 4; i < i1; i += (int)blockDim.x * 4) {
        if (i + 4 <= i1) {
            v4u p4 = *(const v4u*)(region + b0 + i);
            unsigned pk[4] = {p4.x, p4.y, p4.z, p4.w};
            #pragma unroll
            for (int k = 0; k < 4; ++k) {
                unsigned o = (pk[k] >> 15) - (unsigned)lo;
                atomicAdd(&sm[o], __expf(fmaf(pk_like(pk[k]), scale, shift)));
            }
        } else {
            for (int k = 0; i + k < i1; ++k) {
                unsigned pk = region[b0 + i + k];
                unsigned o = (pk >> 15) - (unsigned)lo;
                atomicAdd(&sm[o], __expf(fmaf(pk_like(pk), scale, shift)));
            }
        }
    }
    __syncthreads();

    unsigned* dst = (unsigned*)(slab + ((size_t)p * G + g) * BUCKET);
    for (int i = (int)threadIdx.x * 2; i < BUCKET; i += (int)blockDim.x * 2) {
        unsigned lobits = (unsigned)__half_as_ushort(__float2half(sm[i]));
        unsigned hibits = (unsigned)__half_as_ushort(__float2half(sm[i + 1]));
        __builtin_nontemporal_store(lobits | (hibits << 16), dst + (i >> 1));
    }
}

// ---------------------------------------------------------------------------
// K3b: fold fp16 slabs in fp32: denom[n] = sum_g slab[(p*G+g)*BUCKET + off]
// ---------------------------------------------------------------------------
__global__ void k_fold(const u16* __restrict__ slab,
                       float* __restrict__ denom, int N, int G) {
    int n = blockIdx.x * blockDim.x + threadIdx.x;
    if (n >= N) return;
    int p   = n / BUCKET;
    int off = n - p * BUCKET;
    const u16* s = slab + (size_t)p * G * BUCKET + off;
    float acc = 0.f;
    for (int g = 0; g < G; ++g) {
        u16 bits = __builtin_nontemporal_load(s + (size_t)g * BUCKET);
        acc += __half2float(__ushort_as_half(bits));
    }
    denom[n] = acc;
}

// ---------------------------------------------------------------------------
// K4: out[e] = exp(like*scale+shift) / (1e-12 + denom[node]) from the
// ORDERED plane; denom (400 KB) gathers are L2-resident. (r14-proven)
// ---------------------------------------------------------------------------
__global__ __launch_bounds__(256) void k_normalize(
        const unsigned* __restrict__ plane,
        const double* __restrict__ acc,
        const float* __restrict__ bnw,
        const float* __restrict__ bnb,
        const float* __restrict__ denom,
        float* __restrict__ out,
        int E) {
    __shared__ float2 s_par;
    if (threadIdx.x == 0) s_par = bn_params(acc, bnw, bnb, E);
    __syncthreads();
    const float scale = s_par.x;
    const float shift = s_par.y;
    int e = (blockIdx.x * blockDim.x + threadIdx.x) * 4;
    if (e + 4 <= E) {
        v4u p4 = __builtin_nontemporal_load((const v4u*)(plane + e));
        unsigned pk[4] = {p4.x, p4.y, p4.z, p4.w};
        v4f o;
        o.x = __expf(fmaf(pk_like(pk[0]), scale, shift)) / (1e-12f + denom[pk[0] >> 15]);
        o.y = __expf(fmaf(pk_like(pk[1]), scale, shift)) / (1e-12f + denom[pk[1] >> 15]);
        o.z = __expf(fmaf(pk_like(pk[2]), scale, shift)) / (1e-12f + denom[pk[2] >> 15]);
        o.w = __expf(fmaf(pk_like(pk[3]), scale, shift)) / (1e-12f + denom[pk[3] >> 15]);
        __builtin_nontemporal_store(o, (v4f*)(out + e));
    } else {
        for (; e < E; ++e) {
            unsigned pk = plane[e];
            out[e] = __expf(fmaf(pk_like(pk), scale, shift)) /
                     (1e-12f + denom[pk >> 15]);
        }
    }
}

// Fallback scatter (agent atomics on ordered plane) if ws is too small.
__global__ void k_exp_scatter_agent(const unsigned* __restrict__ plane,
                                    const double* __restrict__ acc,
                                    const float* __restrict__ bnw,
                                    const float* __restrict__ bnb,
                                    float* __restrict__ denom, int E) {
    __shared__ float2 s_par;
    if (threadIdx.x == 0) s_par = bn_params(acc, bnw, bnb, E);
    __syncthreads();
    for (int e = blockIdx.x * blockDim.x + threadIdx.x; e < E;
         e += gridDim.x * blockDim.x) {
        unsigned pk = plane[e];
        atomicAdd(&denom[pk >> 15],
                  __expf(fmaf(pk_like(pk), s_par.x, s_par.y)));
    }
}

extern "C" void kernel_launch(void* const* d_in, const int* in_sizes, int n_in,
                              void* d_out, int out_size, void* d_ws, size_t ws_size,
                              hipStream_t stream) {
    const float* src_emb = (const float*)d_in[0];
    const float* dst_emb = (const float*)d_in[1];
    const float* bnw     = (const float*)d_in[2];
    const float* bnb     = (const float*)d_in[3];
    const int*   gsrc    = (const int*)d_in[4];
    const int*   gdst    = (const int*)d_in[5];

    const int E = in_sizes[4];           // 3,200,000 edges
    const int N = in_sizes[0] / 12;      // 100,000 nodes
    float* out = (float*)d_out;

    const int P = (N + BUCKET - 1) / BUCKET;   // 7 buckets

    // workspace (64B-aligned):
    //   acc(16)|cnt7(28)|cur(28) [memset 128] | denom 4N | qs 16N | qd 16N |
    //   plane 4E | region 4E+pad | slab(u16)
    char* ws = (char*)d_ws;
    double*   acc   = (double*)ws;
    int*      cnt7  = (int*)(ws + 16);
    unsigned* cur   = (unsigned*)(ws + 44);
    size_t    off   = 128;
    float*    denom = (float*)(ws + off);    off += ((size_t)N * 4 + 63) & ~(size_t)63;
    int4*     qs    = (int4*)(ws + off);     off += ((size_t)N * 16 + 63) & ~(size_t)63;
    int4*     qd    = (int4*)(ws + off);     off += ((size_t)N * 16 + 63) & ~(size_t)63;
    unsigned* plane = (unsigned*)(ws + off); off += ((size_t)E * 4 + 63) & ~(size_t)63;
    unsigned* region= (unsigned*)(ws + off); off += ((size_t)E * 4 + (size_t)P * 16 + 63) & ~(size_t)63;
    u16*      slab  = (u16*)(ws + off);

    size_t rem = (ws_size > off) ? ws_size - off : 0;
    int G = 0;
    for (int cand = 64; cand >= 8; cand >>= 1) {
        if ((size_t)P * cand * BUCKET * 2 <= rem) { G = cand; break; }
    }
    bool fast = (G > 0) && (P == 7);

    const int block = 256;

    hipMemsetAsync(ws, 0, 128, stream);

    k_pack_quant<<<(2 * N + block - 1) / block, block, 0, stream>>>(
        src_emb, dst_emb, qs, qd, N);

    int dot_blocks = ((E + 7) / 8 + block - 1) / block;
    k_dot<<<dot_blocks, block, 0, stream>>>(qs, qd, gsrc, gdst, plane, acc,
                                            cnt7, E);

    if (fast) {
        k_split<<<1024, block, 0, stream>>>(plane, cnt7, cur, region, E, P);
        dim3 gsc(G, P);
        k_bucket_scatter<<<gsc, 512, 0, stream>>>(region, cnt7, acc, bnw, bnb,
                                                  slab, E, G, P);
        k_fold<<<(N + block - 1) / block, block, 0, stream>>>(slab, denom, N, G);
    } else {
        hipMemsetAsync(denom, 0, (size_t)N * 4, stream);
        int blocks = min((E + block - 1) / block, 4096);
        k_exp_scatter_agent<<<blocks, block, 0, stream>>>(plane, acc,
                                                          bnw, bnb, denom, E);
    }

    int norm_blocks = ((E + 3) / 4 + block - 1) / block;
    k_normalize<<<norm_blocks, block, 0, stream>>>(plane, acc, bnw, bnb,
                                                   denom, out, E);
}

// Round 18
// 135.193 us; speedup vs baseline: 22.8312x; 22.8312x over previous
//
#include <hip/hip_runtime.h>
#include <hip/hip_fp16.h>

#define BN_EPS 1e-5f
#define BUCKET 16000          // 64,000 B static LDS -> 2 WG/CU (r14-proven)

// 12 dims packed in 16 B: 4 x u32, each = (d0:11b | d1:11b | d2:10b), signed
// fixed point, range +-5.5 (inputs are N(0,1); P(|x|>5.5) ~ 2e-8).
#define QS11 186.0f            // 1023/5.5
#define QS10 92.909090f        // 511/5.5
#define QI11 0.0053763445f     // 5.5/1023
#define QI10 0.0107632094f     // 5.5/511
#define QP11 (QI11*QI11)
#define QP10 (QI10*QI10)

typedef int            v4i __attribute__((ext_vector_type(4)));
typedef unsigned       v4u __attribute__((ext_vector_type(4)));
typedef float          v4f __attribute__((ext_vector_type(4)));
typedef unsigned short u16;

// edge record: pk = (gsrc:17 << 15) | (fp16(like) >> 1)   [like15: 15 bits]
__device__ __forceinline__ float pk_like(unsigned pk) {
    return __half2float(__ushort_as_half((u16)((pk & 0x7FFFu) << 1)));
}

__device__ __forceinline__ float2 bn_params(const double* acc,
                                            const float* bnw,
                                            const float* bnb, int E) {
    double mean = acc[0] / (double)E;
    double var  = acc[1] / (double)E - mean * mean;
    float scale = bnw[0] * rsqrtf((float)var + BN_EPS);
    float shift = bnb[0] - (float)mean * scale;
    return make_float2(scale, shift);
}

__device__ __forceinline__ int qclamp(float x, float s, int lim) {
    int q = (int)rintf(x * s);
    return min(max(q, -lim), lim);
}
__device__ __forceinline__ unsigned enc3(float a, float b, float c) {
    unsigned qa = (unsigned)qclamp(a, QS11, 1023) & 0x7FFu;
    unsigned qb = (unsigned)qclamp(b, QS11, 1023) & 0x7FFu;
    unsigned qc = (unsigned)qclamp(c, QS10, 511)  & 0x3FFu;
    return qa | (qb << 11) | (qc << 22);
}

// ---------------------------------------------------------------------------
// K0: quant-pack BOTH f32 [N][12] tables into 16 B rows (one launch).
// Tables become 2 x 1.6 MB -> both L2-resident on every XCD.
// ---------------------------------------------------------------------------
__global__ void k_pack_quant(const float* __restrict__ src_emb,
                             const float* __restrict__ dst_emb,
                             int4* __restrict__ qs,
                             int4* __restrict__ qd, int N) {
    int t = blockIdx.x * blockDim.x + threadIdx.x;
    if (t >= 2 * N) return;
    int n = (t < N) ? t : t - N;
    const float* r = ((t < N) ? src_emb : dst_emb) + (size_t)n * 12;
    int4* dst = ((t < N) ? qs : qd) + n;
    float v[12];
    #pragma unroll
    for (int j = 0; j < 12; ++j) v[j] = r[j];
    int4 w;
    w.x = (int)enc3(v[0], v[1], v[2]);
    w.y = (int)enc3(v[3], v[4], v[5]);
    w.z = (int)enc3(v[6], v[7], v[8]);
    w.w = (int)enc3(v[9], v[10], v[11]);
    *dst = w;
}

// integer decode-dot of two 16 B rows
__device__ __forceinline__ float qdot(int4 A, int4 B) {
    int aw[4] = {A.x, A.y, A.z, A.w};
    int bw[4] = {B.x, B.y, B.z, B.w};
    int s11 = 0, s10 = 0;
    #pragma unroll
    for (int k = 0; k < 4; ++k) {
        int a0 = (aw[k] << 21) >> 21;
        int a1 = (aw[k] << 10) >> 21;
        int a2 =  aw[k] >> 22;
        int b0 = (bw[k] << 21) >> 21;
        int b1 = (bw[k] << 10) >> 21;
        int b2 =  bw[k] >> 22;
        s11 += a0 * b0 + a1 * b1;
        s10 += a2 * b2;
    }
    return (float)s11 * QP11 + (float)s10 * QP10;
}

// ---------------------------------------------------------------------------
// K1: fused dot, 8 edges/thread (r12/r14-proven, at its L2-gather floor).
// Writes ONE combined u32 plane pk = (gsrc<<15)|(h16>>1).
// ---------------------------------------------------------------------------
__global__ __launch_bounds__(256) void k_dot(
        const int4* __restrict__ qs,
        const int4* __restrict__ qd,
        const int* __restrict__ gsrc,
        const int* __restrict__ gdst,
        unsigned* __restrict__ plane,
        double* __restrict__ acc,   // acc[0]=sum, acc[1]=sumsq
        int E) {
    int e0 = (blockIdx.x * blockDim.x + threadIdx.x) * 8;
    float lsum = 0.f, lsq = 0.f;
    if (e0 + 8 <= E) {
        v4i s0 = __builtin_nontemporal_load((const v4i*)(gsrc + e0));
        v4i s1 = __builtin_nontemporal_load((const v4i*)(gsrc + e0 + 4));
        v4i d0 = __builtin_nontemporal_load((const v4i*)(gdst + e0));
        v4i d1 = __builtin_nontemporal_load((const v4i*)(gdst + e0 + 4));
        int is[8] = {s0.x, s0.y, s0.z, s0.w, s1.x, s1.y, s1.z, s1.w};
        int id[8] = {d0.x, d0.y, d0.z, d0.w, d1.x, d1.y, d1.z, d1.w};
        int4 ra[8], rb[8];
        #pragma unroll
        for (int k = 0; k < 8; ++k) {     // issue all 16 gathers up front
            ra[k] = qs[is[k]];
            rb[k] = qd[id[k]];
        }
        unsigned pk[8];
        #pragma unroll
        for (int k = 0; k < 8; ++k) {
            float d = qdot(ra[k], rb[k]);
            lsum += d;
            lsq  = fmaf(d, d, lsq);
            unsigned h = (unsigned)__half_as_ushort(__float2half(d));
            pk[k] = ((unsigned)is[k] << 15) | (h >> 1);
        }
        v4u o0 = {pk[0], pk[1], pk[2], pk[3]};
        v4u o1 = {pk[4], pk[5], pk[6], pk[7]};
        __builtin_nontemporal_store(o0, (v4u*)(plane + e0));
        __builtin_nontemporal_store(o1, (v4u*)(plane + e0 + 4));
    } else {
        for (int e = e0; e < E; ++e) {
            int gs = gsrc[e];
            float d = qdot(qs[gs], qd[gdst[e]]);
            lsum += d;
            lsq  += d * d;
            unsigned h = (unsigned)__half_as_ushort(__float2half(d));
            plane[e] = ((unsigned)gs << 15) | (h >> 1);
        }
    }
    for (int off = 32; off > 0; off >>= 1) {
        lsum += __shfl_down(lsum, off);
        lsq  += __shfl_down(lsq, off);
    }
    __shared__ float ssum[4], ssq[4];
    int wave = threadIdx.x >> 6, lane = threadIdx.x & 63;
    if (lane == 0) { ssum[wave] = lsum; ssq[wave] = lsq; }
    __syncthreads();
    if (threadIdx.x == 0) {
        float ts = 0.f, tq = 0.f;
        for (int i = 0; i < 4; ++i) { ts += ssum[i]; tq += ssq[i]; }
        atomicAdd(&acc[0], (double)ts);
        atomicAdd(&acc[1], (double)tq);
    }
}

// ---------------------------------------------------------------------------
// K3: LDS-privatized segment sum from the combined plane. NORMAL (cached)
// plane loads: grid (G,P) with blockIdx.x=g fastest puts all 7 bucket-passes
// of slice g on the SAME XCD (XCD = linear%8 = g%8 since 64%8==0), all
// co-resident (448 blocks) -> slice g (200 KB) is fetched once and passes
// 2-7 hit L2. The NT hint used since r5 was defeating exactly this reuse.
// fp16 slab (u16 bits), paired-u32 flush.
// ---------------------------------------------------------------------------
__global__ __launch_bounds__(512) void k_bucket_scatter(
        const unsigned* __restrict__ plane,
        const double* __restrict__ acc,
        const float* __restrict__ bnw,
        const float* __restrict__ bnb,
        u16* __restrict__ slab,   // [(p*G + g) * BUCKET], fp16 bits
        int E, int G) {
    __shared__ float sm[BUCKET];
    __shared__ float2 s_par;
    const int g  = blockIdx.x;
    const int p  = blockIdx.y;
    const int lo = p * BUCKET;

    if (threadIdx.x == 0) s_par = bn_params(acc, bnw, bnb, E);
    for (int i = threadIdx.x; i < BUCKET; i += blockDim.x) sm[i] = 0.f;
    __syncthreads();
    const float scale = s_par.x;
    const float shift = s_par.y;

    int per = (E + G - 1) / G;
    per = (per + 3) & ~3;
    const int s0 = g * per;
    const int s1 = min(s0 + per, E);

    for (int e = s0 + (int)threadIdx.x * 4; e < s1; e += (int)blockDim.x * 4) {
        if (e + 4 <= s1) {
            v4u p4 = *(const v4u*)(plane + e);          // cached load (L2 reuse)
            unsigned pk[4] = {p4.x, p4.y, p4.z, p4.w};
            #pragma unroll
            for (int k = 0; k < 4; ++k) {
                unsigned o = (pk[k] >> 15) - (unsigned)lo;
                if (o < BUCKET)
                    atomicAdd(&sm[o], __expf(fmaf(pk_like(pk[k]), scale, shift)));
            }
        } else {
            for (int k = 0; e + k < s1; ++k) {
                unsigned pk = plane[e + k];
                unsigned o = (pk >> 15) - (unsigned)lo;
                if (o < BUCKET)
                    atomicAdd(&sm[o], __expf(fmaf(pk_like(pk), scale, shift)));
            }
        }
    }
    __syncthreads();

    // paired flush: two fp16 values per u32 store (BUCKET is even)
    unsigned* dst = (unsigned*)(slab + ((size_t)p * G + g) * BUCKET);
    for (int i = (int)threadIdx.x * 2; i < BUCKET; i += (int)blockDim.x * 2) {
        unsigned lobits = (unsigned)__half_as_ushort(__float2half(sm[i]));
        unsigned hibits = (unsigned)__half_as_ushort(__float2half(sm[i + 1]));
        __builtin_nontemporal_store(lobits | (hibits << 16), dst + (i >> 1));
    }
}

// ---------------------------------------------------------------------------
// K3b: fold fp16 slabs in fp32: denom[n] = sum_g slab[(p*G+g)*BUCKET + off]
// ---------------------------------------------------------------------------
__global__ void k_fold(const u16* __restrict__ slab,
                       float* __restrict__ denom, int N, int G) {
    int n = blockIdx.x * blockDim.x + threadIdx.x;
    if (n >= N) return;
    int p   = n / BUCKET;
    int off = n - p * BUCKET;
    const u16* s = slab + (size_t)p * G * BUCKET + off;
    float acc = 0.f;
    for (int g = 0; g < G; ++g) {
        u16 bits = __builtin_nontemporal_load(s + (size_t)g * BUCKET);
        acc += __half2float(__ushort_as_half(bits));
    }
    denom[n] = acc;
}

// ---------------------------------------------------------------------------
// K4: out[e] = exp(like*scale+shift) / (1e-12 + denom[node]) from the plane
// (cached loads -- possible L2 leftovers); denom (400 KB) is L2-resident.
// ---------------------------------------------------------------------------
__global__ __launch_bounds__(256) void k_normalize(
        const unsigned* __restrict__ plane,
        const double* __restrict__ acc,
        const float* __restrict__ bnw,
        const float* __restrict__ bnb,
        const float* __restrict__ denom,
        float* __restrict__ out,
        int E) {
    __shared__ float2 s_par;
    if (threadIdx.x == 0) s_par = bn_params(acc, bnw, bnb, E);
    __syncthreads();
    const float scale = s_par.x;
    const float shift = s_par.y;
    int e = (blockIdx.x * blockDim.x + threadIdx.x) * 4;
    if (e + 4 <= E) {
        v4u p4 = *(const v4u*)(plane + e);
        unsigned pk[4] = {p4.x, p4.y, p4.z, p4.w};
        v4f o;
        o.x = __expf(fmaf(pk_like(pk[0]), scale, shift)) / (1e-12f + denom[pk[0] >> 15]);
        o.y = __expf(fmaf(pk_like(pk[1]), scale, shift)) / (1e-12f + denom[pk[1] >> 15]);
        o.z = __expf(fmaf(pk_like(pk[2]), scale, shift)) / (1e-12f + denom[pk[2] >> 15]);
        o.w = __expf(fmaf(pk_like(pk[3]), scale, shift)) / (1e-12f + denom[pk[3] >> 15]);
        __builtin_nontemporal_store(o, (v4f*)(out + e));
    } else {
        for (; e < E; ++e) {
            unsigned pk = plane[e];
            out[e] = __expf(fmaf(pk_like(pk), scale, shift)) /
                     (1e-12f + denom[pk >> 15]);
        }
    }
}

// Fallback scatter (agent atomics) if ws can't hold the slab.
__global__ void k_exp_scatter_agent(const unsigned* __restrict__ plane,
                                    const double* __restrict__ acc,
                                    const float* __restrict__ bnw,
                                    const float* __restrict__ bnb,
                                    float* __restrict__ denom, int E) {
    __shared__ float2 s_par;
    if (threadIdx.x == 0) s_par = bn_params(acc, bnw, bnb, E);
    __syncthreads();
    for (int e = blockIdx.x * blockDim.x + threadIdx.x; e < E;
         e += gridDim.x * blockDim.x) {
        unsigned pk = plane[e];
        atomicAdd(&denom[pk >> 15],
                  __expf(fmaf(pk_like(pk), s_par.x, s_par.y)));
    }
}

extern "C" void kernel_launch(void* const* d_in, const int* in_sizes, int n_in,
                              void* d_out, int out_size, void* d_ws, size_t ws_size,
                              hipStream_t stream) {
    const float* src_emb = (const float*)d_in[0];
    const float* dst_emb = (const float*)d_in[1];
    const float* bnw     = (const float*)d_in[2];
    const float* bnb     = (const float*)d_in[3];
    const int*   gsrc    = (const int*)d_in[4];
    const int*   gdst    = (const int*)d_in[5];

    const int E = in_sizes[4];           // 3,200,000 edges
    const int N = in_sizes[0] / 12;      // 100,000 nodes
    float* out = (float*)d_out;

    const int P = (N + BUCKET - 1) / BUCKET;   // 7 buckets

    // workspace (64B-aligned): acc | denom 4N | qs 16N | qd 16N | plane 4E | slab(u16)
    char* ws = (char*)d_ws;
    double*   acc   = (double*)ws;
    size_t    off   = 64;
    float*    denom = (float*)(ws + off);    off += ((size_t)N * 4 + 63) & ~(size_t)63;
    int4*     qs    = (int4*)(ws + off);     off += ((size_t)N * 16 + 63) & ~(size_t)63;
    int4*     qd    = (int4*)(ws + off);     off += ((size_t)N * 16 + 63) & ~(size_t)63;
    unsigned* plane = (unsigned*)(ws + off); off += ((size_t)E * 4 + 63) & ~(size_t)63;
    u16*      slab  = (u16*)(ws + off);

    size_t rem = (ws_size > off) ? ws_size - off : 0;
    int G = 0;
    for (int cand = 64; cand >= 8; cand >>= 1) {
        if ((size_t)P * cand * BUCKET * 2 <= rem) { G = cand; break; }
    }

    const int block = 256;

    hipMemsetAsync(ws, 0, 32, stream);

    k_pack_quant<<<(2 * N + block - 1) / block, block, 0, stream>>>(
        src_emb, dst_emb, qs, qd, N);

    int dot_blocks = ((E + 7) / 8 + block - 1) / block;
    k_dot<<<dot_blocks, block, 0, stream>>>(qs, qd, gsrc, gdst, plane, acc, E);

    if (G > 0) {
        dim3 gsc(G, P);
        k_bucket_scatter<<<gsc, 512, 0, stream>>>(plane, acc, bnw, bnb,
                                                  slab, E, G);
        k_fold<<<(N + block - 1) / block, block, 0, stream>>>(slab, denom, N, G);
    } else {
        hipMemsetAsync(denom, 0, (size_t)N * 4, stream);
        int blocks = min((E + block - 1) / block, 4096);
        k_exp_scatter_agent<<<blocks, block, 0, stream>>>(plane, acc,
                                                          bnw, bnb, denom, E);
    }

    int norm_blocks = ((E + 3) / 4 + block - 1) / block;
    k_normalize<<<norm_blocks, block, 0, stream>>>(plane, acc, bnw, bnb,
                                                   denom, out, E);
}